// Round 1
// baseline (2852.596 us; speedup 1.0000x reference)
//
#include <hip/hip_runtime.h>
#include <math.h>

#define N_NODES 50000
#define N_EDGES 500000
#define D 128
#define BE 64      // edges per block
#define KT 32      // K-tile

__device__ __forceinline__ float softplus_f(float v) {
    return fmaxf(v, 0.0f) + log1pf(expf(-fabsf(v)));
}
__device__ __forceinline__ float sigmoid_f(float v) {
    return 1.0f / (1.0f + expf(-v));
}

// Per block: BE edges x 256 outputs (128 from Wf, 128 from Ws), K=384.
// Thread (to=tid&31, te=tid>>5) owns 8 edges (te*8..+7) and 8 outputs:
// f-outputs to*4..to*4+3 and the MATCHING s-outputs (+128) so the
// sigmoid*softplus gate needs no cross-thread exchange.
__global__ __launch_bounds__(256) void edge_msg_kernel(
    const float* __restrict__ x, const float* __restrict__ edge_attr,
    const int* __restrict__ esrc, const int* __restrict__ etgt,
    const float* __restrict__ Wf, const float* __restrict__ bfp,
    const float* __restrict__ Ws, const float* __restrict__ bsp,
    float* __restrict__ agg)
{
    __shared__ float sW[KT][256];   // 32 KB: cols 0..127 = Wf, 128..255 = Ws
    __shared__ float sZ[KT][BE];    // 8 KB: k-major gathered Z tile
    __shared__ int sSrc[BE];
    __shared__ int sTgt[BE];

    const int tid = threadIdx.x;
    const int e0  = blockIdx.x * BE;

    if (tid < BE) {
        int eg = e0 + tid;
        sSrc[tid] = (eg < N_EDGES) ? esrc[eg] : 0;
    } else if (tid < 2 * BE) {
        int t = tid - BE;
        int eg = e0 + t;
        sTgt[t] = (eg < N_EDGES) ? etgt[eg] : 0;
    }
    __syncthreads();

    float acc[8][8];
#pragma unroll
    for (int i = 0; i < 8; i++)
#pragma unroll
        for (int j = 0; j < 8; j++) acc[i][j] = 0.0f;

    const int e_l = tid >> 2;          // 0..63  (Z staging: 4 threads/edge)
    const int kq  = (tid & 3) * 8;     // 0,8,16,24
    const int to  = tid & 31;
    const int te  = tid >> 5;

#pragma unroll 1
    for (int kt = 0; kt < 12; kt++) {
        // ---- stage W tile: 32x256 floats, 8 float4 per thread ----
#pragma unroll
        for (int i = 0; i < 8; i++) {
            int f4  = tid + 256 * i;       // 0..2047
            int row = f4 >> 6;             // 0..31
            int c4  = f4 & 63;             // 0..63
            const float* wp = (c4 < 32)
                ? (Wf + (size_t)(kt * KT + row) * D + (c4 << 2))
                : (Ws + (size_t)(kt * KT + row) * D + ((c4 - 32) << 2));
            *(float4*)&sW[row][c4 << 2] = *(const float4*)wp;
        }
        // ---- stage Z tile (gather): 32 contiguous feats of one source ----
        {
            int eg = e0 + e_l;
            const float* zsrc;
            if (kt < 4)      zsrc = x + (size_t)sSrc[e_l] * D + kt * KT;
            else if (kt < 8) zsrc = x + (size_t)sTgt[e_l] * D + (kt - 4) * KT;
            else             zsrc = edge_attr + (size_t)((eg < N_EDGES) ? eg : 0) * D + (kt - 8) * KT;
            float4 g0 = *(const float4*)(zsrc + kq);
            float4 g1 = *(const float4*)(zsrc + kq + 4);
            sZ[kq + 0][e_l] = g0.x; sZ[kq + 1][e_l] = g0.y;
            sZ[kq + 2][e_l] = g0.z; sZ[kq + 3][e_l] = g0.w;
            sZ[kq + 4][e_l] = g1.x; sZ[kq + 5][e_l] = g1.y;
            sZ[kq + 6][e_l] = g1.z; sZ[kq + 7][e_l] = g1.w;
        }
        __syncthreads();

        // ---- compute: 64 FMA per kk per thread ----
#pragma unroll
        for (int kk = 0; kk < KT; kk++) {
            float4 z0  = *(float4*)&sZ[kk][te * 8];
            float4 z1  = *(float4*)&sZ[kk][te * 8 + 4];
            float4 wf4 = *(float4*)&sW[kk][to * 4];
            float4 ws4 = *(float4*)&sW[kk][128 + to * 4];
            float ze[8] = {z0.x, z0.y, z0.z, z0.w, z1.x, z1.y, z1.z, z1.w};
#pragma unroll
            for (int i = 0; i < 8; i++) {
                acc[i][0] += ze[i] * wf4.x; acc[i][1] += ze[i] * wf4.y;
                acc[i][2] += ze[i] * wf4.z; acc[i][3] += ze[i] * wf4.w;
                acc[i][4] += ze[i] * ws4.x; acc[i][5] += ze[i] * ws4.y;
                acc[i][6] += ze[i] * ws4.z; acc[i][7] += ze[i] * ws4.w;
            }
        }
        __syncthreads();
    }

    // ---- epilogue: gate + scatter-add to source node ----
    float4 bF = *(const float4*)&bfp[to * 4];
    float4 bS = *(const float4*)&bsp[to * 4];
#pragma unroll
    for (int i = 0; i < 8; i++) {
        int e  = te * 8 + i;
        int eg = e0 + e;
        if (eg >= N_EDGES) continue;
        float* arow = agg + (size_t)sSrc[e] * D + to * 4;
        float m0 = sigmoid_f(acc[i][0] + bF.x) * softplus_f(acc[i][4] + bS.x);
        float m1 = sigmoid_f(acc[i][1] + bF.y) * softplus_f(acc[i][5] + bS.y);
        float m2 = sigmoid_f(acc[i][2] + bF.z) * softplus_f(acc[i][6] + bS.z);
        float m3 = sigmoid_f(acc[i][3] + bF.w) * softplus_f(acc[i][7] + bS.w);
        atomicAdd(arow + 0, m0);
        atomicAdd(arow + 1, m1);
        atomicAdd(arow + 2, m2);
        atomicAdd(arow + 3, m3);
    }
}

// Column sums / sumsq over agg [N, 128] -> stats[0..127]=sum, [128..255]=sumsq
__global__ __launch_bounds__(256) void bn_stats_kernel(
    const float* __restrict__ agg, float* __restrict__ stats)
{
    const int o    = threadIdx.x & (D - 1);
    const int half = threadIdx.x >> 7;   // 0/1
    const int rows = (N_NODES + gridDim.x - 1) / gridDim.x;
    int r0 = blockIdx.x * rows;
    int r1 = min(r0 + rows, N_NODES);
    float s = 0.0f, s2 = 0.0f;
    for (int r = r0 + half; r < r1; r += 2) {
        float v = agg[(size_t)r * D + o];
        s += v; s2 += v * v;
    }
    atomicAdd(&stats[o], s);
    atomicAdd(&stats[D + o], s2);
}

__global__ __launch_bounds__(256) void bn_final_kernel(
    const float* __restrict__ x, const float* __restrict__ agg,
    const float* __restrict__ stats,
    const float* __restrict__ gamma, const float* __restrict__ beta,
    float* __restrict__ out)
{
    const int idx = blockIdx.x * blockDim.x + threadIdx.x;  // float4 index
    const int total4 = N_NODES * D / 4;
    if (idx >= total4) return;
    const int c4 = idx & (D / 4 - 1);
    const float inv_n = 1.0f / (float)N_NODES;

    float4 sm = *(const float4*)&stats[c4 * 4];
    float4 sq = *(const float4*)&stats[D + c4 * 4];
    float4 g  = *(const float4*)&gamma[c4 * 4];
    float4 b  = *(const float4*)&beta[c4 * 4];
    float4 xv = ((const float4*)x)[idx];
    float4 av = ((const float4*)agg)[idx];

    float4 o;
    {
        float mean = sm.x * inv_n;
        float var  = sq.x * inv_n - mean * mean;
        float is   = rsqrtf(var + 1e-5f) * g.x;
        o.x = softplus_f(xv.x + (av.x - mean) * is + b.x);
    }
    {
        float mean = sm.y * inv_n;
        float var  = sq.y * inv_n - mean * mean;
        float is   = rsqrtf(var + 1e-5f) * g.y;
        o.y = softplus_f(xv.y + (av.y - mean) * is + b.y);
    }
    {
        float mean = sm.z * inv_n;
        float var  = sq.z * inv_n - mean * mean;
        float is   = rsqrtf(var + 1e-5f) * g.z;
        o.z = softplus_f(xv.z + (av.z - mean) * is + b.z);
    }
    {
        float mean = sm.w * inv_n;
        float var  = sq.w * inv_n - mean * mean;
        float is   = rsqrtf(var + 1e-5f) * g.w;
        o.w = softplus_f(xv.w + (av.w - mean) * is + b.w);
    }
    ((float4*)out)[idx] = o;
}

extern "C" void kernel_launch(void* const* d_in, const int* in_sizes, int n_in,
                              void* d_out, int out_size, void* d_ws, size_t ws_size,
                              hipStream_t stream) {
    const float* x         = (const float*)d_in[0];
    const float* edge_attr = (const float*)d_in[1];
    const int*   esrc      = (const int*)d_in[2];
    const int*   etgt      = (const int*)d_in[3];
    const float* Wf        = (const float*)d_in[4];
    const float* bf_       = (const float*)d_in[5];
    const float* Ws        = (const float*)d_in[6];
    const float* bs_       = (const float*)d_in[7];
    const float* gamma     = (const float*)d_in[8];
    const float* beta      = (const float*)d_in[9];
    float* out   = (float*)d_out;
    float* agg   = (float*)d_ws;
    float* stats = agg + (size_t)N_NODES * D;

    // zero agg + stats (ws is poisoned 0xAA before every call)
    hipMemsetAsync(d_ws, 0, ((size_t)N_NODES * D + 2 * D) * sizeof(float), stream);

    edge_msg_kernel<<<(N_EDGES + BE - 1) / BE, 256, 0, stream>>>(
        x, edge_attr, esrc, etgt, Wf, bf_, Ws, bs_, agg);
    bn_stats_kernel<<<256, 256, 0, stream>>>(agg, stats);
    bn_final_kernel<<<(N_NODES * D / 4 + 255) / 256, 256, 0, stream>>>(
        x, agg, stats, gamma, beta, out);
}

// Round 2
// 765.027 us; speedup vs baseline: 3.7288x; 3.7288x over previous
//
#include <hip/hip_runtime.h>
#include <math.h>
#include <stdint.h>

#define N_NODES 50000
#define N_EDGES 500000
#define D 128
#define BE 64          // edges per block
#define KT 64          // K per LDS tile
#define NKT 6          // 384 / 64
#define WROW 72        // padded LDS/global tile row length in bf16 (64 real + 8 pad)
#define WSLAB (256 * WROW)   // bf16 elems per kt slab of Wt_tiled

typedef __attribute__((ext_vector_type(8))) short bf16x8;
typedef __attribute__((ext_vector_type(4))) float floatx4;

__device__ __forceinline__ float softplus_f(float v) {
    return fmaxf(v, 0.0f) + log1pf(expf(-fabsf(v)));
}
__device__ __forceinline__ float sigmoid_f(float v) {
    return 1.0f / (1.0f + expf(-v));
}
__device__ __forceinline__ unsigned short f2bf(float f) {
    union { float f; uint32_t u; } c; c.f = f;
    uint32_t u = c.u;
    return (unsigned short)((u + 0x7FFFu + ((u >> 16) & 1u)) >> 16);
}

// Build Wt_tiled: 6 slabs (kt) x 256 rows (n: 0..127 = Wf col, 128..255 = Ws col)
// x 72 bf16 (k = kt*64 + 0..63, then 8 zero pad). Contiguous-with-pads so the
// main kernel can stage each 36864B slab via global_load_lds verbatim.
__global__ __launch_bounds__(256) void wt_prepass(
    const float* __restrict__ Wf, const float* __restrict__ Ws,
    unsigned short* __restrict__ Wt)
{
    int t = blockIdx.x * blockDim.x + threadIdx.x;
    if (t >= 256 * 24) return;
    int n   = t / 24;          // 0..255
    int k16 = t % 24;          // 0..23
    int k0  = k16 * 16;
    const float* src = (n < 128) ? (Wf + n) : (Ws + (n - 128));
    unsigned short tmp[16];
#pragma unroll
    for (int j = 0; j < 16; j++) tmp[j] = f2bf(src[(size_t)(k0 + j) * D]);
    int kt = k0 >> 6;
    int kk = k0 & 63;
    unsigned short* dst = Wt + (size_t)kt * WSLAB + (size_t)n * WROW + kk;
    *(uint4*)(dst)     = *(uint4*)(tmp);
    *(uint4*)(dst + 8) = *(uint4*)(tmp + 8);
    if (kk == 48) {            // zero the 8-bf16 pad of this row
        uint4 z = {0, 0, 0, 0};
        *(uint4*)(dst + 16) = z;
    }
}

// Per block: 64 edges x 256 outputs (128 f + 128 s), K=384, bf16 MFMA 16x16x32.
// 4 waves partition N: wave w owns f-cols [w*32, w*32+32) and s-cols
// [128+w*32, ...) so gating pairs acc[mt][nt] (f) with acc[mt][nt+2] (s)
// on the same lane/register.
__global__ __launch_bounds__(256) void edge_msg_mfma(
    const float* __restrict__ x, const float* __restrict__ edge_attr,
    const int* __restrict__ esrc, const int* __restrict__ etgt,
    const unsigned short* __restrict__ Wt,
    const float* __restrict__ bfp, const float* __restrict__ bsp,
    float* __restrict__ agg)
{
    __shared__ unsigned short sW[WSLAB];       // 36864 B
    __shared__ unsigned short sZ[BE * WROW];   // 9216 B
    __shared__ int sSrc[BE];
    __shared__ int sTgt[BE];

    const int tid  = threadIdx.x;
    const int lane = tid & 63;
    const int w    = tid >> 6;
    const int e0   = blockIdx.x * BE;

    if (tid < BE) {
        sSrc[tid] = (e0 + tid < N_EDGES) ? esrc[e0 + tid] : 0;
    } else if (tid < 2 * BE) {
        int m = tid - BE;
        sTgt[m] = (e0 + m < N_EDGES) ? etgt[e0 + m] : 0;
    }
    __syncthreads();

    floatx4 acc[4][4];
#pragma unroll
    for (int mt = 0; mt < 4; mt++)
#pragma unroll
        for (int nt = 0; nt < 4; nt++) {
            floatx4 z = {0.f, 0.f, 0.f, 0.f};
            acc[mt][nt] = z;
        }

    const int zm = tid >> 2;         // 0..63 (edge row staged by this thread)
    const int zk = (tid & 3) * 16;   // fp32 element offset within the 64-k tile

#pragma unroll 1
    for (int kt = 0; kt < NKT; kt++) {
        // ---- stage W slab via async global->LDS (16B/lane, layout verbatim) ----
        {
            const char* gbase = (const char*)(Wt + (size_t)kt * WSLAB) + w * 9216 + lane * 16;
            char* lbase = (char*)sW + w * 9216;   // wave-uniform LDS base
#pragma unroll
            for (int i = 0; i < 9; i++) {
                __builtin_amdgcn_global_load_lds(
                    (const __attribute__((address_space(1))) void*)(gbase + i * 1024),
                    (__attribute__((address_space(3))) void*)(lbase + i * 1024),
                    16, 0, 0);
            }
        }
        // ---- stage Z tile: gather fp32, cvt RNE->bf16, ds_write_b128 x2 ----
        {
            const float* zsrc;
            int half = (kt & 1) * 64;
            if (kt < 2)      zsrc = x + (size_t)sSrc[zm] * D + half;
            else if (kt < 4) zsrc = x + (size_t)sTgt[zm] * D + half;
            else {
                int eg = e0 + zm;
                zsrc = edge_attr + (size_t)(eg < N_EDGES ? eg : 0) * D + half;
            }
            float4 f0 = *(const float4*)(zsrc + zk);
            float4 f1 = *(const float4*)(zsrc + zk + 4);
            float4 f2 = *(const float4*)(zsrc + zk + 8);
            float4 f3 = *(const float4*)(zsrc + zk + 12);
            unsigned short tmp[16];
            tmp[0] = f2bf(f0.x); tmp[1] = f2bf(f0.y); tmp[2]  = f2bf(f0.z); tmp[3]  = f2bf(f0.w);
            tmp[4] = f2bf(f1.x); tmp[5] = f2bf(f1.y); tmp[6]  = f2bf(f1.z); tmp[7]  = f2bf(f1.w);
            tmp[8] = f2bf(f2.x); tmp[9] = f2bf(f2.y); tmp[10] = f2bf(f2.z); tmp[11] = f2bf(f2.w);
            tmp[12] = f2bf(f3.x); tmp[13] = f2bf(f3.y); tmp[14] = f2bf(f3.z); tmp[15] = f2bf(f3.w);
            unsigned short* dz = sZ + zm * WROW + zk;
            *(uint4*)(dz)     = *(uint4*)(tmp);
            *(uint4*)(dz + 8) = *(uint4*)(tmp + 8);
        }
        __syncthreads();

        // ---- MFMA: 2 k-steps of 32; 4 m-tiles x (2 f + 2 s) n-tiles ----
#pragma unroll
        for (int ks = 0; ks < 2; ks++) {
            const int kb = ks * 32 + (lane >> 4) * 8;   // bf16 offset in row
            bf16x8 afr[4];
#pragma unroll
            for (int mt = 0; mt < 4; mt++)
                afr[mt] = *(const bf16x8*)(sZ + (mt * 16 + (lane & 15)) * WROW + kb);
            bf16x8 bfr[4];
#pragma unroll
            for (int nt = 0; nt < 4; nt++) {
                int n = (nt < 2) ? (w * 32 + nt * 16 + (lane & 15))
                                 : (128 + w * 32 + (nt - 2) * 16 + (lane & 15));
                bfr[nt] = *(const bf16x8*)(sW + n * WROW + kb);
            }
#pragma unroll
            for (int mt = 0; mt < 4; mt++)
#pragma unroll
                for (int nt = 0; nt < 4; nt++)
                    acc[mt][nt] = __builtin_amdgcn_mfma_f32_16x16x32_bf16(
                        afr[mt], bfr[nt], acc[mt][nt], 0, 0, 0);
        }
        __syncthreads();
    }

    // ---- epilogue: bias + gate + atomic scatter to source nodes ----
#pragma unroll
    for (int nt = 0; nt < 2; nt++) {
        const int col = w * 32 + nt * 16 + (lane & 15);
        const float bF = bfp[col];
        const float bS = bsp[col];
#pragma unroll
        for (int mt = 0; mt < 4; mt++) {
#pragma unroll
            for (int r = 0; r < 4; r++) {
                int mm = mt * 16 + (lane >> 4) * 4 + r;
                int eg = e0 + mm;
                if (eg >= N_EDGES) continue;
                float f = acc[mt][nt][r] + bF;
                float s = acc[mt][nt + 2][r] + bS;
                float msg = sigmoid_f(f) * softplus_f(s);
                atomicAdd(agg + (size_t)sSrc[mm] * D + col, msg);
            }
        }
    }
}

// Column sums / sumsq over agg [N,128] -> stats[0..127]=sum, [128..255]=sumsq
__global__ __launch_bounds__(256) void bn_stats_kernel(
    const float* __restrict__ agg, float* __restrict__ stats)
{
    const int o    = threadIdx.x & (D - 1);
    const int half = threadIdx.x >> 7;
    const int rows = (N_NODES + gridDim.x - 1) / gridDim.x;
    int r0 = blockIdx.x * rows;
    int r1 = min(r0 + rows, N_NODES);
    float s = 0.0f, s2 = 0.0f;
    for (int r = r0 + half; r < r1; r += 2) {
        float v = agg[(size_t)r * D + o];
        s += v; s2 += v * v;
    }
    atomicAdd(&stats[o], s);
    atomicAdd(&stats[D + o], s2);
}

__global__ __launch_bounds__(256) void bn_final_kernel(
    const float* __restrict__ x, const float* __restrict__ agg,
    const float* __restrict__ stats,
    const float* __restrict__ gamma, const float* __restrict__ beta,
    float* __restrict__ out)
{
    const int idx = blockIdx.x * blockDim.x + threadIdx.x;  // float4 index
    const int total4 = N_NODES * D / 4;
    if (idx >= total4) return;
    const int c4 = idx & (D / 4 - 1);
    const float inv_n = 1.0f / (float)N_NODES;

    float4 sm = *(const float4*)&stats[c4 * 4];
    float4 sq = *(const float4*)&stats[D + c4 * 4];
    float4 g  = *(const float4*)&gamma[c4 * 4];
    float4 b  = *(const float4*)&beta[c4 * 4];
    float4 xv = ((const float4*)x)[idx];
    float4 av = ((const float4*)agg)[idx];

    float4 o;
    {
        float mean = sm.x * inv_n, var = sq.x * inv_n - mean * mean;
        float is = rsqrtf(var + 1e-5f) * g.x;
        o.x = softplus_f(xv.x + (av.x - mean) * is + b.x);
    }
    {
        float mean = sm.y * inv_n, var = sq.y * inv_n - mean * mean;
        float is = rsqrtf(var + 1e-5f) * g.y;
        o.y = softplus_f(xv.y + (av.y - mean) * is + b.y);
    }
    {
        float mean = sm.z * inv_n, var = sq.z * inv_n - mean * mean;
        float is = rsqrtf(var + 1e-5f) * g.z;
        o.z = softplus_f(xv.z + (av.z - mean) * is + b.z);
    }
    {
        float mean = sm.w * inv_n, var = sq.w * inv_n - mean * mean;
        float is = rsqrtf(var + 1e-5f) * g.w;
        o.w = softplus_f(xv.w + (av.w - mean) * is + b.w);
    }
    ((float4*)out)[idx] = o;
}

extern "C" void kernel_launch(void* const* d_in, const int* in_sizes, int n_in,
                              void* d_out, int out_size, void* d_ws, size_t ws_size,
                              hipStream_t stream) {
    const float* x         = (const float*)d_in[0];
    const float* edge_attr = (const float*)d_in[1];
    const int*   esrc      = (const int*)d_in[2];
    const int*   etgt      = (const int*)d_in[3];
    const float* Wf        = (const float*)d_in[4];
    const float* bf_       = (const float*)d_in[5];
    const float* Ws        = (const float*)d_in[6];
    const float* bs_       = (const float*)d_in[7];
    const float* gamma     = (const float*)d_in[8];
    const float* beta      = (const float*)d_in[9];
    float* out = (float*)d_out;

    float* agg   = (float*)d_ws;                                // 25,600,000 B
    float* stats = agg + (size_t)N_NODES * D;                   // 1024 B
    unsigned short* Wt = (unsigned short*)(stats + 2 * D);      // 6*256*72*2 B

    // zero agg + stats (ws poisoned 0xAA before every call)
    hipMemsetAsync(d_ws, 0, ((size_t)N_NODES * D + 2 * D) * sizeof(float), stream);

    wt_prepass<<<24, 256, 0, stream>>>(Wf, Ws, Wt);
    edge_msg_mfma<<<(N_EDGES + BE - 1) / BE, 256, 0, stream>>>(
        x, edge_attr, esrc, etgt, Wt, bf_, bs_, agg);
    bn_stats_kernel<<<256, 256, 0, stream>>>(agg, stats);
    bn_final_kernel<<<(N_NODES * D / 4 + 255) / 256, 256, 0, stream>>>(
        x, agg, stats, gamma, beta, out);
}

// Round 3
// 693.566 us; speedup vs baseline: 4.1129x; 1.1030x over previous
//
#include <hip/hip_runtime.h>
#include <math.h>
#include <stdint.h>

#define N_NODES 50000
#define N_EDGES 500000
#define D 128
#define BE 64          // edges per block
#define KT 64          // K per LDS tile
#define NKT 6          // 384 / 64
#define WROW 72        // padded tile row length in bf16 (64 real + 8 pad)
#define WSLAB (256 * WROW)   // bf16 elems per kt slab of Wt_tiled
#define LOG2E 1.4426950408889634f
#define LN2   0.6931471805599453f

typedef __attribute__((ext_vector_type(8))) short bf16x8;
typedef __attribute__((ext_vector_type(4))) float floatx4;

// ---- fast math: native v_exp_f32 / v_log_f32 / v_rcp_f32 (1-ulp) ----
__device__ __forceinline__ float fast_sigmoid(float v) {
    return __builtin_amdgcn_rcpf(1.0f + __builtin_amdgcn_exp2f(-v * LOG2E));
}
__device__ __forceinline__ float fast_softplus(float v) {
    float t = __builtin_amdgcn_exp2f(-fabsf(v) * LOG2E);
    return fmaxf(v, 0.0f) + __builtin_amdgcn_logf(1.0f + t) * LN2;
}
// round-half-up bf16 pair pack: 3 VALU per 2 elements (add,add,v_perm)
__device__ __forceinline__ uint32_t pack_bf16(float a, float b) {
    union { float f; uint32_t u; } ca, cb; ca.f = a; cb.f = b;
    return __builtin_amdgcn_perm(cb.u + 0x8000u, ca.u + 0x8000u, 0x07060302);
}

// Build Wt_tiled: 6 slabs (kt) x 256 rows (n: 0..127=Wf col, 128..255=Ws col)
// x 72 bf16 (k = kt*64+0..63 then 8 zero pad). Coalesced reads: block b owns
// k = b*16..b*16+15; thread = n, consecutive lanes read consecutive n.
__global__ __launch_bounds__(256) void wt_prepass(
    const float* __restrict__ Wf, const float* __restrict__ Ws,
    unsigned short* __restrict__ Wt)
{
    const int n  = threadIdx.x;        // 0..255
    const int k0 = blockIdx.x * 16;    // 24 blocks
    const float* src = (n < 128) ? (Wf + n) : (Ws + (n - 128));
    unsigned short tmp[16];
#pragma unroll
    for (int j = 0; j < 16; j++) {
        union { float f; uint32_t u; } c; c.f = src[(size_t)(k0 + j) * D];
        tmp[j] = (unsigned short)((c.u + 0x8000u) >> 16);
    }
    const int kt = k0 >> 6;
    const int kk = k0 & 63;
    unsigned short* dst = Wt + (size_t)kt * WSLAB + (size_t)n * WROW + kk;
    *(uint4*)(dst)     = *(uint4*)(tmp);
    *(uint4*)(dst + 8) = *(uint4*)(tmp + 8);
    if (kk == 48) {        // zero the 8-bf16 row pad
        uint4 z = {0, 0, 0, 0};
        *(uint4*)(dst + 16) = z;
    }
}

// Per block: 64 edges x 256 outputs (128 f + 128 s), K=384, bf16 MFMA 16x16x32.
// Wave w owns f-cols [w*32,w*32+32) and matching s-cols so gating pairs
// acc[mt][nt] (f) with acc[mt][nt+2] (s) on the same lane/register.
__global__ __launch_bounds__(256) void edge_msg_mfma(
    const float* __restrict__ x, const float* __restrict__ edge_attr,
    const int* __restrict__ esrc, const int* __restrict__ etgt,
    const unsigned short* __restrict__ Wt,
    const float* __restrict__ bfp, const float* __restrict__ bsp,
    float* __restrict__ agg)
{
    __shared__ unsigned short sW[WSLAB];       // 36864 B
    __shared__ unsigned short sZ[BE * WROW];   // 9216 B
    __shared__ int sSrc[BE];
    __shared__ int sTgt[BE];

    const int tid  = threadIdx.x;
    const int lane = tid & 63;
    const int w    = tid >> 6;
    const int e0   = blockIdx.x * BE;

    if (tid < BE) {
        sSrc[tid] = (e0 + tid < N_EDGES) ? esrc[e0 + tid] : 0;
    } else if (tid < 2 * BE) {
        int m = tid - BE;
        sTgt[m] = (e0 + m < N_EDGES) ? etgt[e0 + m] : 0;
    }
    __syncthreads();

    floatx4 acc[4][4];
#pragma unroll
    for (int mt = 0; mt < 4; mt++)
#pragma unroll
        for (int nt = 0; nt < 4; nt++) {
            floatx4 z = {0.f, 0.f, 0.f, 0.f};
            acc[mt][nt] = z;
        }

    const int zm = tid >> 2;         // edge row staged by this thread
    const int zk = (tid & 3) * 16;   // fp32 element offset in the 64-k tile

#pragma unroll 1
    for (int kt = 0; kt < NKT; kt++) {
        // ---- stage W slab via async global->LDS (16B/lane, verbatim) ----
        {
            const char* gbase = (const char*)(Wt + (size_t)kt * WSLAB) + w * 9216 + lane * 16;
            char* lbase = (char*)sW + w * 9216;   // wave-uniform LDS base
#pragma unroll
            for (int i = 0; i < 9; i++) {
                __builtin_amdgcn_global_load_lds(
                    (const __attribute__((address_space(1))) void*)(gbase + i * 1024),
                    (__attribute__((address_space(3))) void*)(lbase + i * 1024),
                    16, 0, 0);
            }
        }
        // ---- stage Z tile: gather fp32, pack bf16 (v_perm), ds_write ----
        {
            const float* zsrc;
            int half = (kt & 1) * 64;
            if (kt < 2)      zsrc = x + (size_t)sSrc[zm] * D + half;
            else if (kt < 4) zsrc = x + (size_t)sTgt[zm] * D + half;
            else {
                int eg = e0 + zm;
                zsrc = edge_attr + (size_t)(eg < N_EDGES ? eg : 0) * D + half;
            }
            float4 f0 = *(const float4*)(zsrc + zk);
            float4 f1 = *(const float4*)(zsrc + zk + 4);
            float4 f2 = *(const float4*)(zsrc + zk + 8);
            float4 f3 = *(const float4*)(zsrc + zk + 12);
            uint4 lo, hi;
            lo.x = pack_bf16(f0.x, f0.y); lo.y = pack_bf16(f0.z, f0.w);
            lo.z = pack_bf16(f1.x, f1.y); lo.w = pack_bf16(f1.z, f1.w);
            hi.x = pack_bf16(f2.x, f2.y); hi.y = pack_bf16(f2.z, f2.w);
            hi.z = pack_bf16(f3.x, f3.y); hi.w = pack_bf16(f3.z, f3.w);
            uint32_t* dz = (uint32_t*)(sZ + (size_t)zm * WROW) + (zk >> 1);
            *(uint4*)(dz)     = lo;
            *(uint4*)(dz + 4) = hi;
        }
        __syncthreads();

        // ---- MFMA: 2 k-steps of 32; 4 m-tiles x (2 f + 2 s) n-tiles ----
#pragma unroll
        for (int ks = 0; ks < 2; ks++) {
            const int kb = ks * 32 + (lane >> 4) * 8;   // bf16 offset in row
            bf16x8 afr[4];
#pragma unroll
            for (int mt = 0; mt < 4; mt++)
                afr[mt] = *(const bf16x8*)(sZ + (mt * 16 + (lane & 15)) * WROW + kb);
            bf16x8 bfr[4];
#pragma unroll
            for (int nt = 0; nt < 4; nt++) {
                int n = (nt < 2) ? (w * 32 + nt * 16 + (lane & 15))
                                 : (128 + w * 32 + (nt - 2) * 16 + (lane & 15));
                bfr[nt] = *(const bf16x8*)(sW + n * WROW + kb);
            }
#pragma unroll
            for (int mt = 0; mt < 4; mt++)
#pragma unroll
                for (int nt = 0; nt < 4; nt++)
                    acc[mt][nt] = __builtin_amdgcn_mfma_f32_16x16x32_bf16(
                        afr[mt], bfr[nt], acc[mt][nt], 0, 0, 0);
        }
        __syncthreads();
    }

    // ---- epilogue: bias + gate (native exp/log/rcp) + atomic scatter ----
#pragma unroll
    for (int nt = 0; nt < 2; nt++) {
        const int col = w * 32 + nt * 16 + (lane & 15);
        const float bF = bfp[col];
        const float bS = bsp[col];
#pragma unroll
        for (int mt = 0; mt < 4; mt++) {
#pragma unroll
            for (int r = 0; r < 4; r++) {
                int mm = mt * 16 + (lane >> 4) * 4 + r;
                int eg = e0 + mm;
                if (eg >= N_EDGES) continue;
                float f = acc[mt][nt][r] + bF;
                float s = acc[mt][nt + 2][r] + bS;
                float msg = fast_sigmoid(f) * fast_softplus(s);
                atomicAdd(agg + (size_t)sSrc[mm] * D + col, msg);
            }
        }
    }
}

// Column sums/sumsq over agg [N,128] -> stats[0..127]=sum, [128..255]=sumsq.
// LDS-reduce the two row-halves, then 256 atomics per block (grid 128).
#define STATS_BLOCKS 128
__global__ __launch_bounds__(256) void bn_stats_kernel(
    const float* __restrict__ agg, float* __restrict__ stats)
{
    __shared__ float red[256];
    const int o    = threadIdx.x & (D - 1);
    const int half = threadIdx.x >> 7;
    const int rows = (N_NODES + STATS_BLOCKS - 1) / STATS_BLOCKS;
    int r0 = blockIdx.x * rows;
    int r1 = min(r0 + rows, N_NODES);
    float s = 0.0f, s2 = 0.0f;
    for (int r = r0 + half; r < r1; r += 2) {
        float v = agg[(size_t)r * D + o];
        s += v; s2 += v * v;
    }
    red[threadIdx.x] = s;
    __syncthreads();
    float stot = (threadIdx.x < 128) ? red[threadIdx.x] + red[threadIdx.x + 128] : 0.0f;
    __syncthreads();
    red[threadIdx.x] = s2;
    __syncthreads();
    if (threadIdx.x < 128) {
        float s2tot = red[threadIdx.x] + red[threadIdx.x + 128];
        atomicAdd(&stats[o], stot);
        atomicAdd(&stats[D + o], s2tot);
    }
}

__global__ __launch_bounds__(256) void bn_final_kernel(
    const float* __restrict__ x, const float* __restrict__ agg,
    const float* __restrict__ stats,
    const float* __restrict__ gamma, const float* __restrict__ beta,
    float* __restrict__ out)
{
    const int idx = blockIdx.x * blockDim.x + threadIdx.x;  // float4 index
    const int total4 = N_NODES * D / 4;
    if (idx >= total4) return;
    const int c4 = idx & (D / 4 - 1);
    const float inv_n = 1.0f / (float)N_NODES;

    float4 sm = *(const float4*)&stats[c4 * 4];
    float4 sq = *(const float4*)&stats[D + c4 * 4];
    float4 g  = *(const float4*)&gamma[c4 * 4];
    float4 b  = *(const float4*)&beta[c4 * 4];
    float4 xv = ((const float4*)x)[idx];
    float4 av = ((const float4*)agg)[idx];

    float4 o;
    {
        float mean = sm.x * inv_n, var = sq.x * inv_n - mean * mean;
        float is = rsqrtf(var + 1e-5f) * g.x;
        o.x = fast_softplus(xv.x + (av.x - mean) * is + b.x);
    }
    {
        float mean = sm.y * inv_n, var = sq.y * inv_n - mean * mean;
        float is = rsqrtf(var + 1e-5f) * g.y;
        o.y = fast_softplus(xv.y + (av.y - mean) * is + b.y);
    }
    {
        float mean = sm.z * inv_n, var = sq.z * inv_n - mean * mean;
        float is = rsqrtf(var + 1e-5f) * g.z;
        o.z = fast_softplus(xv.z + (av.z - mean) * is + b.z);
    }
    {
        float mean = sm.w * inv_n, var = sq.w * inv_n - mean * mean;
        float is = rsqrtf(var + 1e-5f) * g.w;
        o.w = fast_softplus(xv.w + (av.w - mean) * is + b.w);
    }
    ((float4*)out)[idx] = o;
}

extern "C" void kernel_launch(void* const* d_in, const int* in_sizes, int n_in,
                              void* d_out, int out_size, void* d_ws, size_t ws_size,
                              hipStream_t stream) {
    const float* x         = (const float*)d_in[0];
    const float* edge_attr = (const float*)d_in[1];
    const int*   esrc      = (const int*)d_in[2];
    const int*   etgt      = (const int*)d_in[3];
    const float* Wf        = (const float*)d_in[4];
    const float* bf_       = (const float*)d_in[5];
    const float* Ws        = (const float*)d_in[6];
    const float* bs_       = (const float*)d_in[7];
    const float* gamma     = (const float*)d_in[8];
    const float* beta      = (const float*)d_in[9];
    float* out = (float*)d_out;

    float* agg   = (float*)d_ws;                                // 25,600,000 B
    float* stats = agg + (size_t)N_NODES * D;                   // 1024 B
    unsigned short* Wt = (unsigned short*)(stats + 2 * D);      // 6*256*72*2 B

    // zero agg + stats (ws poisoned 0xAA before every call)
    hipMemsetAsync(d_ws, 0, ((size_t)N_NODES * D + 2 * D) * sizeof(float), stream);

    wt_prepass<<<24, 256, 0, stream>>>(Wf, Ws, Wt);
    edge_msg_mfma<<<(N_EDGES + BE - 1) / BE, 256, 0, stream>>>(
        x, edge_attr, esrc, etgt, Wt, bf_, bs_, agg);
    bn_stats_kernel<<<STATS_BLOCKS, 256, 0, stream>>>(agg, stats);
    bn_final_kernel<<<(N_NODES * D / 4 + 255) / 256, 256, 0, stream>>>(
        x, agg, stats, gamma, beta, out);
}